// Round 7
// baseline (92.317 us; speedup 1.0000x reference)
//
#include <hip/hip_runtime.h>
#include <hip/hip_bf16.h>

// Bilinear CNN pooling: dotted[b,c,d] = sum_x L[b,x,c]*R[b,x,d]  (B=32, X=12544, C=128)
// then signed-sqrt + global L2-normalize per batch.
//
// Round 7: r6 + intra-block K-split. 8 waves = (substep 0/1) x (2x2 quadrants
// of 64x64). Per-wave LDS reads drop 12->8 b128/iter (block: 96->64); one-time
// 64KB LDS merge of the two substep-halves at the end. Everything else r6.

#define NK      8             // K-chunks per batch
#define KC      1568          // 12544 / 8
#define BK      32            // K per tile
#define NT      49            // KC / BK
#define BATCH   32
#define CDIM    128
#define XDIM    12544

typedef __bf16 bf16x8 __attribute__((ext_vector_type(8)));
typedef float  f32x16 __attribute__((ext_vector_type(16)));

// 16 MB partial buffer + per-segment sumsq; fully rewritten before read each launch.
__device__ float g_part[(size_t)NK * BATCH * CDIM * CDIM];
__device__ float g_ssq[BATCH * 16];

// Split 8 f32 -> RNE-bf16 hi + trunc-bf16 lo, packed into uint4s (validated r1-r6).
__device__ __forceinline__ void split8(const float* f, uint4& hi, uint4& lo) {
  uint xh[8], xl[8];
#pragma unroll
  for (int i = 0; i < 8; ++i) {
    uint u = __float_as_uint(f[i]);
    uint r = u + 0x7FFFu + ((u >> 16) & 1u);        // RNE bf16 in top 16 bits
    xh[i] = r;
    float hif = __uint_as_float(r & 0xFFFF0000u);    // exact hi value
    xl[i] = __float_as_uint(f[i] - hif);             // exact residual, trunc on pack
  }
  hi.x = __builtin_amdgcn_perm(xh[1], xh[0], 0x07060302u);
  hi.y = __builtin_amdgcn_perm(xh[3], xh[2], 0x07060302u);
  hi.z = __builtin_amdgcn_perm(xh[5], xh[4], 0x07060302u);
  hi.w = __builtin_amdgcn_perm(xh[7], xh[6], 0x07060302u);
  lo.x = __builtin_amdgcn_perm(xl[1], xl[0], 0x07060302u);
  lo.y = __builtin_amdgcn_perm(xl[3], xl[2], 0x07060302u);
  lo.z = __builtin_amdgcn_perm(xl[5], xl[4], 0x07060302u);
  lo.w = __builtin_amdgcn_perm(xl[7], xl[6], 0x07060302u);
}

// LDS 16B-unit index for (column c, k-half kh) within one 16-k substep (r4-r6 validated).
__device__ __forceinline__ int ldsu(int c, int kh) {
  return ((c << 1) | kh) ^ ((c >> 2) & 7);
}

// region base (in uint4 units) for [set][sub][mat: 0=A,1=B][hilo]
#define REGN(set, sub, mat, hilo) (((((((set)*2 + (sub))*2 + (mat))*2) + (hilo)) * 256))

// ---------------------------------------------------------------------------
// Kernel 1: per (chunk, batch): partial[c][d] = sum_{k in chunk} L[k][c]*R[k][d]
// 512 threads = 8 waves = (sub 0/1) x (qr 0/1) x (qc 0/1); each wave: 64x64
// quadrant over its 16-k substep; merge halves via LDS at the end.
// ---------------------------------------------------------------------------
__global__ __launch_bounds__(512, 2)
void bcnn_gemm_kernel(const float* __restrict__ L, const float* __restrict__ R) {
  __shared__ uint4 smem[4096];   // 64 KB: [set][sub][A/B][hi/lo][256 units]

  const int chunk = blockIdx.x;      // 0..7
  const int b     = blockIdx.y;
  const int t     = threadIdx.x;
  const int l     = t & 63;
  const int w     = t >> 6;
  const int lc    = l & 31;
  const int hh    = l >> 5;          // k-half within the wave's substep
  const int sub   = w >> 2;          // which 16-k substep this wave computes
  const int q     = w & 3;
  const int qr    = q >> 1;          // 64-row quadrant
  const int qc    = q & 1;           // 64-col quadrant

  // staging: thread owns column sc, k-rows sh*8 .. sh*8+7 of each 32-k tile
  const int sc   = t & 127;
  const int sh   = t >> 7;           // 0..3
  const int ssub = sh >> 1;          // substep region this thread stages
  const int wu   = ldsu(sc, sh & 1);

  const float* gL = L + ((size_t)b * XDIM + (size_t)chunk * KC + sh * 8) * CDIM + sc;
  const float* gR = R + ((size_t)b * XDIM + (size_t)chunk * KC + sh * 8) * CDIM + sc;

  // fragment units (within this wave's substep region)
  const int uA0 = ldsu(qr * 64 + lc,      hh);
  const int uA1 = ldsu(qr * 64 + 32 + lc, hh);
  const int uB0 = ldsu(qc * 64 + lc,      hh);
  const int uB1 = ldsu(qc * 64 + 32 + lc, hh);

  f32x16 acc00 = {}, acc01 = {}, acc10 = {}, acc11 = {};

  // three static register-parity sets (tile s has parity s % 3)
  float rlA[8], rrA[8], rlB[8], rrB[8], rlC[8], rrC[8];

#define LOADR(rl, rr, s)                                                        \
  do {                                                                          \
    const float* pL_ = gL + (size_t)(s) * BK * CDIM;                            \
    const float* pR_ = gR + (size_t)(s) * BK * CDIM;                            \
    _Pragma("unroll")                                                           \
    for (int i = 0; i < 8; ++i) { rl[i] = pL_[i * CDIM]; rr[i] = pR_[i * CDIM]; } \
  } while (0)

#define WRITE(rl, rr, set)                                                      \
  do {                                                                          \
    uint4 hi_, lo_;                                                             \
    split8(rl, hi_, lo_);                                                       \
    smem[REGN(set, ssub, 0, 0) + wu] = hi_;                                     \
    smem[REGN(set, ssub, 0, 1) + wu] = lo_;                                     \
    split8(rr, hi_, lo_);                                                       \
    smem[REGN(set, ssub, 1, 0) + wu] = hi_;                                     \
    smem[REGN(set, ssub, 1, 1) + wu] = lo_;                                     \
  } while (0)

#define COMPUTE(set)                                                            \
  do {                                                                          \
    bf16x8 ah0 = *(const bf16x8*)&smem[REGN(set, sub, 0, 0) + uA0];             \
    bf16x8 al0 = *(const bf16x8*)&smem[REGN(set, sub, 0, 1) + uA0];             \
    bf16x8 ah1 = *(const bf16x8*)&smem[REGN(set, sub, 0, 0) + uA1];             \
    bf16x8 al1 = *(const bf16x8*)&smem[REGN(set, sub, 0, 1) + uA1];             \
    bf16x8 bh0 = *(const bf16x8*)&smem[REGN(set, sub, 1, 0) + uB0];             \
    bf16x8 bl0 = *(const bf16x8*)&smem[REGN(set, sub, 1, 1) + uB0];             \
    bf16x8 bh1 = *(const bf16x8*)&smem[REGN(set, sub, 1, 0) + uB1];             \
    bf16x8 bl1 = *(const bf16x8*)&smem[REGN(set, sub, 1, 1) + uB1];             \
    acc00 = __builtin_amdgcn_mfma_f32_32x32x16_bf16(ah0, bh0, acc00, 0, 0, 0);  \
    acc01 = __builtin_amdgcn_mfma_f32_32x32x16_bf16(ah0, bh1, acc01, 0, 0, 0);  \
    acc10 = __builtin_amdgcn_mfma_f32_32x32x16_bf16(ah1, bh0, acc10, 0, 0, 0);  \
    acc11 = __builtin_amdgcn_mfma_f32_32x32x16_bf16(ah1, bh1, acc11, 0, 0, 0);  \
    acc00 = __builtin_amdgcn_mfma_f32_32x32x16_bf16(ah0, bl0, acc00, 0, 0, 0);  \
    acc01 = __builtin_amdgcn_mfma_f32_32x32x16_bf16(ah0, bl1, acc01, 0, 0, 0);  \
    acc10 = __builtin_amdgcn_mfma_f32_32x32x16_bf16(ah1, bl0, acc10, 0, 0, 0);  \
    acc11 = __builtin_amdgcn_mfma_f32_32x32x16_bf16(ah1, bl1, acc11, 0, 0, 0);  \
    acc00 = __builtin_amdgcn_mfma_f32_32x32x16_bf16(al0, bh0, acc00, 0, 0, 0);  \
    acc01 = __builtin_amdgcn_mfma_f32_32x32x16_bf16(al0, bh1, acc01, 0, 0, 0);  \
    acc10 = __builtin_amdgcn_mfma_f32_32x32x16_bf16(al1, bh0, acc10, 0, 0, 0);  \
    acc11 = __builtin_amdgcn_mfma_f32_32x32x16_bf16(al1, bh1, acc11, 0, 0, 0);  \
  } while (0)

#define BAR()                                                                   \
  do {                                                                          \
    asm volatile("s_waitcnt lgkmcnt(0)" ::: "memory");                          \
    __builtin_amdgcn_s_barrier();                                               \
  } while (0)

  // prologue: tiles 0,1,2 in flight; write tile 0
  LOADR(rlA, rrA, 0);
  LOADR(rlB, rrB, 1);
  LOADR(rlC, rrC, 2);
  WRITE(rlA, rrA, 0);
  BAR();

  // steady state (identical schedule to r6): 6-unrolled, 3-deep lookahead
  for (int it = 0; it < 7; ++it) {
    const int s0 = 6 * it;
    /* s0+0 */ LOADR(rlA, rrA, s0 + 3); COMPUTE(0); WRITE(rlB, rrB, 1); BAR();
    /* s0+1 */ LOADR(rlB, rrB, s0 + 4); COMPUTE(1); WRITE(rlC, rrC, 0); BAR();
    /* s0+2 */ LOADR(rlC, rrC, s0 + 5); COMPUTE(0); WRITE(rlA, rrA, 1); BAR();
    /* s0+3 */ LOADR(rlA, rrA, s0 + 6); COMPUTE(1); WRITE(rlB, rrB, 0); BAR();
    /* s0+4 */ LOADR(rlB, rrB, s0 + 7); COMPUTE(0); WRITE(rlC, rrC, 1); BAR();
    /* s0+5 */ LOADR(rlC, rrC, s0 + 8); COMPUTE(1); WRITE(rlA, rrA, 0); BAR();
  }
  // peeled tail: s = 42..48 (loads stop at tile 48)
  /* s=42 */ LOADR(rlA, rrA, 45); COMPUTE(0); WRITE(rlB, rrB, 1); BAR();
  /* s=43 */ LOADR(rlB, rrB, 46); COMPUTE(1); WRITE(rlC, rrC, 0); BAR();
  /* s=44 */ LOADR(rlC, rrC, 47); COMPUTE(0); WRITE(rlA, rrA, 1); BAR();
  /* s=45 */ LOADR(rlA, rrA, 48); COMPUTE(1); WRITE(rlB, rrB, 0); BAR();
  /* s=46 */ COMPUTE(0); WRITE(rlC, rrC, 1); BAR();
  /* s=47 */ COMPUTE(1); WRITE(rlA, rrA, 0); BAR();
  /* s=48 */ COMPUTE(0);

#undef LOADR
#undef WRITE
#undef COMPUTE

  // ---- merge substep halves: waves 4-7 dump accs, waves 0-3 add ----
  BAR();                              // all LDS reads of the last tile done
  float* fs = (float*)smem;
  if (w >= 4) {
    const int base = (w - 4) * 4096 + l;
#pragma unroll
    for (int r = 0; r < 16; ++r) {
      fs[base +    0 + r * 64] = acc00[r];
      fs[base + 1024 + r * 64] = acc01[r];
      fs[base + 2048 + r * 64] = acc10[r];
      fs[base + 3072 + r * 64] = acc11[r];
    }
  }
  BAR();                              // merge data visible
  if (w < 4) {
    const int base = w * 4096 + l;
#pragma unroll
    for (int r = 0; r < 16; ++r) {
      acc00[r] += fs[base +    0 + r * 64];
      acc01[r] += fs[base + 1024 + r * 64];
      acc10[r] += fs[base + 2048 + r * 64];
      acc11[r] += fs[base + 3072 + r * 64];
    }
    // C/D layout (HW-validated r1-r6): col = lane&31, row = (r&3)+8*(r>>2)+4*hh
    float* outp = g_part + (((size_t)chunk * BATCH + b) << 14);
#pragma unroll
    for (int r = 0; r < 16; ++r) {
      const int row = (r & 3) + ((r >> 2) << 3) + (hh << 2);
      const int r0 = qr * 64 + row;
      const int c0 = qc * 64 + lc;
      outp[(size_t)(r0)      * CDIM + c0]      = acc00[r];
      outp[(size_t)(r0)      * CDIM + c0 + 32] = acc01[r];
      outp[(size_t)(r0 + 32) * CDIM + c0]      = acc10[r];
      outp[(size_t)(r0 + 32) * CDIM + c0 + 32] = acc11[r];
    }
  }
#undef BAR
}

// ---------------------------------------------------------------------------
// Kernel 2a: sum NK partials, signed-sqrt, write sqrted, per-segment sumsq.
// ---------------------------------------------------------------------------
__global__ void bcnn_sqrt_kernel(float* __restrict__ out) {
  const int b   = blockIdx.y;
  const int seg = blockIdx.x;
  const int t   = threadIdx.x;
  const int idx = seg * 1024 + t * 4;

  float4 v = {0.f, 0.f, 0.f, 0.f};
#pragma unroll
  for (int ch = 0; ch < NK; ++ch) {
    const float4 p = *(const float4*)&g_part[(((size_t)ch * BATCH + b) << 14) + idx];
    v.x += p.x; v.y += p.y; v.z += p.z; v.w += p.w;
  }
  float4 sv;
  {
    float a;
    a = sqrtf(fabsf(v.x) + 1e-9f); sv.x = (v.x > 0.f) ? a : ((v.x < 0.f) ? -a : 0.f);
    a = sqrtf(fabsf(v.y) + 1e-9f); sv.y = (v.y > 0.f) ? a : ((v.y < 0.f) ? -a : 0.f);
    a = sqrtf(fabsf(v.z) + 1e-9f); sv.z = (v.z > 0.f) ? a : ((v.z < 0.f) ? -a : 0.f);
    a = sqrtf(fabsf(v.w) + 1e-9f); sv.w = (v.w > 0.f) ? a : ((v.w < 0.f) ? -a : 0.f);
  }
  *(float4*)&out[((size_t)b << 14) + idx] = sv;

  float ss = sv.x * sv.x + sv.y * sv.y + sv.z * sv.z + sv.w * sv.w;
#pragma unroll
  for (int o = 32; o > 0; o >>= 1) ss += __shfl_down(ss, o, 64);
  __shared__ float red[4];
  if ((t & 63) == 0) red[t >> 6] = ss;
  __syncthreads();
  if (t == 0) g_ssq[b * 16 + seg] = red[0] + red[1] + red[2] + red[3];
}

// ---------------------------------------------------------------------------
// Kernel 2b: scale by rsqrt(max(sumsq, 1e-12))
// ---------------------------------------------------------------------------
__global__ void bcnn_scale_kernel(float* __restrict__ out) {
  const int b   = blockIdx.y;
  const int seg = blockIdx.x;
  const int t   = threadIdx.x;

  float tot = 0.f;
#pragma unroll
  for (int i = 0; i < 16; ++i) tot += g_ssq[b * 16 + i];
  const float scale = rsqrtf(fmaxf(tot, 1e-12f));

  const size_t base = ((size_t)b << 14) + seg * 1024 + t * 4;
  float4 v = *(float4*)&out[base];
  v.x *= scale; v.y *= scale; v.z *= scale; v.w *= scale;
  *(float4*)&out[base] = v;
}

extern "C" void kernel_launch(void* const* d_in, const int* in_sizes, int n_in,
                              void* d_out, int out_size, void* d_ws, size_t ws_size,
                              hipStream_t stream) {
  const float* L = (const float*)d_in[0];
  const float* R = (const float*)d_in[1];
  float* out = (float*)d_out;

  dim3 g1(NK, BATCH);
  bcnn_gemm_kernel<<<g1, 512, 0, stream>>>(L, R);

  dim3 g2(16, BATCH);
  bcnn_sqrt_kernel<<<g2, 256, 0, stream>>>(out);
  bcnn_scale_kernel<<<g2, 256, 0, stream>>>(out);
}